// Round 1
// baseline (2640.991 us; speedup 1.0000x reference)
//
#include <hip/hip_runtime.h>
#include <math.h>

#define T_ 4096
#define C_ 768
#define H_ 12
#define D_ 64
#define TC_ ((size_t)T_ * C_)

// ---------------------------------------------------------------------------
// GEMM: Y[M,N] = A[M,K] @ W[N,K]^T + bias[N]
// Both A and W are read row-wise (coalesced) since torch Linear is x @ W^T.
// 64x64 block tile, BK=16, 256 threads, 4x4 micro-tile per thread.
// LDS layout transposed [k][m] with +4 pad so the inner loop does two
// float4 (b128) LDS reads per k. ~conflict-free (stride 68 floats).
// ---------------------------------------------------------------------------
__global__ __launch_bounds__(256) void gemm_bt_kernel(
    const float* __restrict__ A, const float* __restrict__ W,
    const float* __restrict__ bias, float* __restrict__ Y,
    int M, int N, int K)
{
    __shared__ float As[16][68];
    __shared__ float Bs[16][68];
    const int tid = threadIdx.x;
    const int tx = tid & 15;        // n-dir 0..15
    const int ty = tid >> 4;        // m-dir 0..15
    const int bm = blockIdx.x * 64;
    const int bn = blockIdx.y * 64;

    float c[4][4];
#pragma unroll
    for (int i = 0; i < 4; ++i)
#pragma unroll
        for (int j = 0; j < 4; ++j) c[i][j] = 0.f;

    const int lr = tid >> 2;          // 0..63 (row within tile)
    const int lc = (tid & 3) << 2;    // 0,4,8,12 (k offset within BK)
    const float* Arow = A + (size_t)(bm + lr) * K + lc;
    const float* Wrow = W + (size_t)(bn + lr) * K + lc;

    for (int kk = 0; kk < K; kk += 16) {
        float4 a4 = *(const float4*)(Arow + kk);
        float4 b4 = *(const float4*)(Wrow + kk);
        As[lc + 0][lr] = a4.x; As[lc + 1][lr] = a4.y;
        As[lc + 2][lr] = a4.z; As[lc + 3][lr] = a4.w;
        Bs[lc + 0][lr] = b4.x; Bs[lc + 1][lr] = b4.y;
        Bs[lc + 2][lr] = b4.z; Bs[lc + 3][lr] = b4.w;
        __syncthreads();
#pragma unroll
        for (int k = 0; k < 16; ++k) {
            float4 av = *(const float4*)&As[k][ty << 2];
            float4 bv = *(const float4*)&Bs[k][tx << 2];
            float a0 = av.x, a1 = av.y, a2 = av.z, a3 = av.w;
            float b0 = bv.x, b1 = bv.y, b2 = bv.z, b3 = bv.w;
            c[0][0] = fmaf(a0, b0, c[0][0]); c[0][1] = fmaf(a0, b1, c[0][1]);
            c[0][2] = fmaf(a0, b2, c[0][2]); c[0][3] = fmaf(a0, b3, c[0][3]);
            c[1][0] = fmaf(a1, b0, c[1][0]); c[1][1] = fmaf(a1, b1, c[1][1]);
            c[1][2] = fmaf(a1, b2, c[1][2]); c[1][3] = fmaf(a1, b3, c[1][3]);
            c[2][0] = fmaf(a2, b0, c[2][0]); c[2][1] = fmaf(a2, b1, c[2][1]);
            c[2][2] = fmaf(a2, b2, c[2][2]); c[2][3] = fmaf(a2, b3, c[2][3]);
            c[3][0] = fmaf(a3, b0, c[3][0]); c[3][1] = fmaf(a3, b1, c[3][1]);
            c[3][2] = fmaf(a3, b2, c[3][2]); c[3][3] = fmaf(a3, b3, c[3][3]);
        }
        __syncthreads();
    }

#pragma unroll
    for (int i = 0; i < 4; ++i) {
        const int row = bm + (ty << 2) + i;
#pragma unroll
        for (int j = 0; j < 4; ++j) {
            const int col = bn + (tx << 2) + j;
            Y[(size_t)row * N + col] = c[i][j] + bias[col];
        }
    }
}

// ---------------------------------------------------------------------------
// Flash attention, fp32. One block = (head h, 64-row Q tile). 256 threads.
// Thread owns q-row (tid>>2) entirely in registers (64 f32) and the output
// slice d0 = (tid&3)*16 .. +15. Iterates 64-row K/V tiles staged in LDS.
// Online softmax (running m, l) — mathematically identical to full softmax.
// ---------------------------------------------------------------------------
__global__ __launch_bounds__(256) void attn_kernel(
    const float* __restrict__ Q, const float* __restrict__ K,
    const float* __restrict__ V, float* __restrict__ O)
{
    __shared__ float Ks[64][68];
    __shared__ float Vs[64][68];
    __shared__ float Ps[64][68];

    const int tid  = threadIdx.x;
    const int h    = blockIdx.y;
    const int q0   = blockIdx.x * 64;
    const int row  = tid >> 2;      // 0..63
    const int slot = tid & 3;       // 0..3
    const float scale = 0.125f;     // 1/sqrt(64)

    // q row -> registers
    float q[64];
    const float* qp = Q + (size_t)(q0 + row) * C_ + h * D_;
#pragma unroll
    for (int i = 0; i < 16; ++i) {
        float4 t = *(const float4*)(qp + i * 4);
        q[i * 4 + 0] = t.x; q[i * 4 + 1] = t.y;
        q[i * 4 + 2] = t.z; q[i * 4 + 3] = t.w;
    }

    float acc[16];
#pragma unroll
    for (int i = 0; i < 16; ++i) acc[i] = 0.f;
    float m = -INFINITY, l = 0.f;

    for (int kv0 = 0; kv0 < T_; kv0 += 64) {
        // stage K,V tiles (64 rows x 64 cols)
        const float* kp = K + (size_t)(kv0 + row) * C_ + h * D_;
        const float* vp = V + (size_t)(kv0 + row) * C_ + h * D_;
#pragma unroll
        for (int i = 0; i < 4; ++i) {
            const int col = slot * 16 + i * 4;
            *(float4*)&Ks[row][col] = *(const float4*)(kp + col);
            *(float4*)&Vs[row][col] = *(const float4*)(vp + col);
        }
        __syncthreads();

        // scores for this thread's 16 columns
        float s[16];
#pragma unroll
        for (int j = 0; j < 16; ++j) {
            const int col = slot * 16 + j;
            float a = 0.f;
#pragma unroll
            for (int d = 0; d < 64; d += 4) {
                float4 k4 = *(const float4*)&Ks[col][d];
                a = fmaf(q[d + 0], k4.x, a);
                a = fmaf(q[d + 1], k4.y, a);
                a = fmaf(q[d + 2], k4.z, a);
                a = fmaf(q[d + 3], k4.w, a);
            }
            s[j] = a * scale;
        }

        // row max across the 4 slot-threads (consecutive lanes)
        float mt = s[0];
#pragma unroll
        for (int j = 1; j < 16; ++j) mt = fmaxf(mt, s[j]);
        mt = fmaxf(mt, __shfl_xor(mt, 1));
        mt = fmaxf(mt, __shfl_xor(mt, 2));
        const float mnew = fmaxf(m, mt);
        const float f = __expf(m - mnew);   // m=-inf first iter -> 0

        float psum = 0.f;
#pragma unroll
        for (int j = 0; j < 16; ++j) {
            const float p = __expf(s[j] - mnew);
            Ps[row][slot * 16 + j] = p;
            psum += p;
        }
        psum += __shfl_xor(psum, 1);
        psum += __shfl_xor(psum, 2);
        l = l * f + psum;
        m = mnew;
#pragma unroll
        for (int i = 0; i < 16; ++i) acc[i] *= f;
        __syncthreads();   // Ps visible to all slots

        // PV: acc[d0..d0+15] += sum_kv P[row][kv] * V[kv][d]
        const int d0 = slot * 16;
#pragma unroll 8
        for (int kv = 0; kv < 64; ++kv) {
            const float p = Ps[row][kv];
#pragma unroll
            for (int i = 0; i < 16; i += 4) {
                float4 v4 = *(const float4*)&Vs[kv][d0 + i];
                acc[i + 0] = fmaf(p, v4.x, acc[i + 0]);
                acc[i + 1] = fmaf(p, v4.y, acc[i + 1]);
                acc[i + 2] = fmaf(p, v4.z, acc[i + 2]);
                acc[i + 3] = fmaf(p, v4.w, acc[i + 3]);
            }
        }
        __syncthreads();   // before next tile overwrites Ks/Vs/Ps
    }

    const float inv = 1.f / l;
    float* op = O + (size_t)(q0 + row) * C_ + h * D_ + slot * 16;
#pragma unroll
    for (int i = 0; i < 16; i += 4) {
        float4 o4;
        o4.x = acc[i + 0] * inv; o4.y = acc[i + 1] * inv;
        o4.z = acc[i + 2] * inv; o4.w = acc[i + 3] * inv;
        *(float4*)(op + i) = o4;
    }
}

// ---------------------------------------------------------------------------
extern "C" void kernel_launch(void* const* d_in, const int* in_sizes, int n_in,
                              void* d_out, int out_size, void* d_ws, size_t ws_size,
                              hipStream_t stream) {
    (void)in_sizes; (void)n_in; (void)out_size; (void)ws_size;
    const float* x  = (const float*)d_in[0];
    const float* Wq = (const float*)d_in[1];
    const float* bq = (const float*)d_in[2];
    const float* Wk = (const float*)d_in[3];
    const float* bk = (const float*)d_in[4];
    const float* Wv = (const float*)d_in[5];
    const float* bv = (const float*)d_in[6];
    const float* Wo = (const float*)d_in[7];
    const float* bo = (const float*)d_in[8];
    float* out = (float*)d_out;

    float* ws  = (float*)d_ws;
    float* Q   = ws;
    float* Kt  = ws + TC_;
    float* Vt  = ws + 2 * TC_;
    float* ctx = ws + 3 * TC_;

    dim3 gg(T_ / 64, C_ / 64);   // 64 x 12
    // QKV projections
    gemm_bt_kernel<<<gg, 256, 0, stream>>>(x, Wq, bq, Q,  T_, C_, C_);
    gemm_bt_kernel<<<gg, 256, 0, stream>>>(x, Wk, bk, Kt, T_, C_, C_);
    gemm_bt_kernel<<<gg, 256, 0, stream>>>(x, Wv, bv, Vt, T_, C_, C_);
    // attention
    dim3 ga(T_ / 64, H_);        // 64 x 12
    attn_kernel<<<ga, 256, 0, stream>>>(Q, Kt, Vt, ctx);
    // output projection
    gemm_bt_kernel<<<gg, 256, 0, stream>>>(ctx, Wo, bo, out, T_, C_, C_);
}

// Round 2
// 188.325 us; speedup vs baseline: 14.0236x; 14.0236x over previous
//
#include <hip/hip_runtime.h>
#include <math.h>

#define T_ 4096
#define C_ 768
#define H_ 12
#define D_ 64
#define TC_ ((size_t)T_ * C_)
#define CC_ ((size_t)C_ * C_)
#define LDK 72   // padded LDS row length (bf16 elems): 144 B = 36 dwords -> bank walk 4/row

typedef __attribute__((ext_vector_type(8))) __bf16 bf16x8;
typedef __attribute__((ext_vector_type(4))) float f32x4;
typedef __attribute__((ext_vector_type(8))) unsigned short u16x8;

static __device__ __forceinline__ unsigned short f2bf(float f) {
    // round-to-nearest-even fp32 -> bf16
    unsigned int u = __builtin_bit_cast(unsigned int, f);
    u += 0x7FFFu + ((u >> 16) & 1u);
    return (unsigned short)(u >> 16);
}

// ---------------------------------------------------------------------------
// fp32 -> bf16 elementwise convert (vectorized), n4 = n/4
// ---------------------------------------------------------------------------
__global__ void f2b_kernel(const float* __restrict__ in,
                           unsigned short* __restrict__ out, int n4) {
    int i = blockIdx.x * blockDim.x + threadIdx.x;
    const int stride = gridDim.x * blockDim.x;
    for (; i < n4; i += stride) {
        float4 v = ((const float4*)in)[i];
        ushort4 o;
        o.x = f2bf(v.x); o.y = f2bf(v.y); o.z = f2bf(v.z); o.w = f2bf(v.w);
        ((ushort4*)out)[i] = o;
    }
}

// ---------------------------------------------------------------------------
// bf16 MFMA GEMM: Y[M,N] = (A[M,K] @ W[N,K]^T + bias) * oscale
// 64x64 tile, 4 waves; wave w owns rows [w*16, w*16+16). 16x16x32 MFMA.
// Fragment layout (gfx950): A-frag lane l holds A[l&15][8*(l>>4)+i];
// B-frag lane l holds B[8*(l>>4)+i][l&15]; D: col=l&15, row=4*(l>>4)+reg.
// MODE 0: f32 [M][N];  1: bf16 [M][N];  2: bf16 transposed per head Vt[n][t]
// ---------------------------------------------------------------------------
template <int MODE>
__global__ __launch_bounds__(256) void gemm16(
    const unsigned short* __restrict__ A, const unsigned short* __restrict__ W,
    const float* __restrict__ bias, void* __restrict__ Yv,
    int M, int N, int K, float oscale)
{
    __shared__ unsigned short As[64 * LDK];
    __shared__ unsigned short Ws[64 * LDK];
    const int tid = threadIdx.x;
    const int wave = tid >> 6, lane = tid & 63;
    const int lq = lane & 15, lg = lane >> 4;
    const int bm = blockIdx.x * 64, bn = blockIdx.y * 64;
    const int srow = tid >> 2, sblk = tid & 3;   // staging: row, 16-elem block

    f32x4 acc[4] = {};

    const unsigned short* Ag = A + (size_t)(bm + srow) * K + sblk * 16;
    const unsigned short* Wg = W + (size_t)(bn + srow) * K + sblk * 16;

    for (int kb = 0; kb < K; kb += 64) {
        u16x8 a0 = *(const u16x8*)(Ag + kb);
        u16x8 a1 = *(const u16x8*)(Ag + kb + 8);
        u16x8 w0 = *(const u16x8*)(Wg + kb);
        u16x8 w1 = *(const u16x8*)(Wg + kb + 8);
        __syncthreads();   // previous iteration's consumers done
        *(u16x8*)&As[srow * LDK + sblk * 16] = a0;
        *(u16x8*)&As[srow * LDK + sblk * 16 + 8] = a1;
        *(u16x8*)&Ws[srow * LDK + sblk * 16] = w0;
        *(u16x8*)&Ws[srow * LDK + sblk * 16 + 8] = w1;
        __syncthreads();
#pragma unroll
        for (int ks = 0; ks < 2; ++ks) {
            bf16x8 af = *(const bf16x8*)&As[(wave * 16 + lq) * LDK + ks * 32 + lg * 8];
#pragma unroll
            for (int nt = 0; nt < 4; ++nt) {
                bf16x8 wf = *(const bf16x8*)&Ws[(nt * 16 + lq) * LDK + ks * 32 + lg * 8];
                acc[nt] = __builtin_amdgcn_mfma_f32_16x16x32_bf16(af, wf, acc[nt], 0, 0, 0);
            }
        }
    }

    const int m0 = bm + wave * 16 + lg * 4;   // 4 consecutive output rows (reg r)
#pragma unroll
    for (int nt = 0; nt < 4; ++nt) {
        const int n = bn + nt * 16 + lq;
        const float b = bias[n];
        if (MODE == 0) {
            float* Y = (float*)Yv;
#pragma unroll
            for (int r = 0; r < 4; ++r)
                Y[(size_t)(m0 + r) * N + n] = (acc[nt][r] + b) * oscale;
        } else if (MODE == 1) {
            unsigned short* Y = (unsigned short*)Yv;
#pragma unroll
            for (int r = 0; r < 4; ++r)
                Y[(size_t)(m0 + r) * N + n] = f2bf((acc[nt][r] + b) * oscale);
        } else {
            // Vt[h][d][t] flat = n*T + t ; 4 consecutive t -> one 8B store
            unsigned short* Y = (unsigned short*)Yv;
            ushort4 o;
            o.x = f2bf((acc[nt][0] + b) * oscale);
            o.y = f2bf((acc[nt][1] + b) * oscale);
            o.z = f2bf((acc[nt][2] + b) * oscale);
            o.w = f2bf((acc[nt][3] + b) * oscale);
            *(ushort4*)&Y[(size_t)n * T_ + m0] = o;
        }
    }
}

// ---------------------------------------------------------------------------
// Flash attention, bf16 MFMA. Block = (64 q-rows, head); 4 waves, wave owns 16 q.
// Swapped QK^T: S^T = mfma(A=K, B=Q^T) so lane holds all scores of q-row (lane&15).
// PV: O^T = mfma(A=V^T, B=P^T). Q pre-scaled by 1/8 in projection.
// K staged natural [kv][d]; V staged from head-transposed Vt[h][d][t].
// ---------------------------------------------------------------------------
__global__ __launch_bounds__(256) void attn16(
    const unsigned short* __restrict__ Qb, const unsigned short* __restrict__ Kb,
    const unsigned short* __restrict__ Vtb, unsigned short* __restrict__ ctx)
{
    __shared__ unsigned short Ks[64 * LDK];     // [kv][d]
    __shared__ unsigned short Vs[64 * LDK];     // [d][kv]
    __shared__ unsigned short Ps[4][16 * LDK];  // per wave: [q][kv]

    const int tid = threadIdx.x;
    const int wave = tid >> 6, lane = tid & 63;
    const int lq = lane & 15, lg = lane >> 4;
    const int h = blockIdx.y;
    const int q0 = blockIdx.x * 64 + wave * 16;
    const int srow = tid >> 2, sblk = tid & 3;

    // Q B-frags hoisted: lane holds Q[q0+lq][ks*32 + 8*lg + i]
    const unsigned short* qp = Qb + (size_t)(q0 + lq) * C_ + h * D_ + lg * 8;
    const bf16x8 qf0 = *(const bf16x8*)qp;
    const bf16x8 qf1 = *(const bf16x8*)(qp + 32);

    f32x4 oacc[4] = {};
    float mrun = -3.4e38f, lrun = 0.f;

    const unsigned short* kg = Kb + (size_t)srow * C_ + h * D_ + sblk * 16;
    const unsigned short* vg = Vtb + (size_t)(h * D_ + srow) * T_ + sblk * 16;

    for (int kv0 = 0; kv0 < T_; kv0 += 64) {
        // issue global loads early (overlap prev PV)
        u16x8 k0 = *(const u16x8*)(kg + (size_t)kv0 * C_);
        u16x8 k1 = *(const u16x8*)(kg + (size_t)kv0 * C_ + 8);
        u16x8 v0 = *(const u16x8*)(vg + kv0);
        u16x8 v1 = *(const u16x8*)(vg + kv0 + 8);
        __syncthreads();   // prev tile fully consumed
        *(u16x8*)&Ks[srow * LDK + sblk * 16] = k0;
        *(u16x8*)&Ks[srow * LDK + sblk * 16 + 8] = k1;
        *(u16x8*)&Vs[srow * LDK + sblk * 16] = v0;
        *(u16x8*)&Vs[srow * LDK + sblk * 16 + 8] = v1;
        __syncthreads();   // staged

        // S^T tiles: t-th tile = kv rows [t*16, t*16+16)
        f32x4 sacc[4] = {};
#pragma unroll
        for (int t = 0; t < 4; ++t) {
            bf16x8 a0 = *(const bf16x8*)&Ks[(t * 16 + lq) * LDK + lg * 8];
            sacc[t] = __builtin_amdgcn_mfma_f32_16x16x32_bf16(a0, qf0, sacc[t], 0, 0, 0);
            bf16x8 a1 = *(const bf16x8*)&Ks[(t * 16 + lq) * LDK + 32 + lg * 8];
            sacc[t] = __builtin_amdgcn_mfma_f32_16x16x32_bf16(a1, qf1, sacc[t], 0, 0, 0);
        }

        // online softmax for q-row (lane&15); lane holds s[kv = t*16 + 4*lg + r]
        float s[16];
        float mt = -3.4e38f;
#pragma unroll
        for (int t = 0; t < 4; ++t)
#pragma unroll
            for (int r = 0; r < 4; ++r) {
                const float v = sacc[t][r];
                s[t * 4 + r] = v;
                mt = fmaxf(mt, v);
            }
        mt = fmaxf(mt, __shfl_xor(mt, 16));
        mt = fmaxf(mt, __shfl_xor(mt, 32));
        const float mnew = fmaxf(mrun, mt);
        const float fsc = __expf(mrun - mnew);   // first tile: exp(-inf)=0
        mrun = mnew;
        float psum = 0.f;
#pragma unroll
        for (int i = 0; i < 16; ++i) { s[i] = __expf(s[i] - mnew); psum += s[i]; }
        psum += __shfl_xor(psum, 16);
        psum += __shfl_xor(psum, 32);
        lrun = lrun * fsc + psum;
#pragma unroll
        for (int t = 0; t < 4; ++t)
#pragma unroll
            for (int r = 0; r < 4; ++r) oacc[t][r] *= fsc;

        // write P (bf16) to per-wave LDS: row=q (lane&15), cols t*16+4*lg+{0..3}
#pragma unroll
        for (int t = 0; t < 4; ++t) {
            ushort4 o;
            o.x = f2bf(s[t * 4 + 0]); o.y = f2bf(s[t * 4 + 1]);
            o.z = f2bf(s[t * 4 + 2]); o.w = f2bf(s[t * 4 + 3]);
            *(ushort4*)&Ps[wave][lq * LDK + t * 16 + lg * 4] = o;
        }
        __syncthreads();   // P visible; K reads done

        // O^T += V^T @ P^T : dg-th tile = d rows [dg*16, dg*16+16)
#pragma unroll
        for (int ks = 0; ks < 2; ++ks) {
            bf16x8 pf = *(const bf16x8*)&Ps[wave][lq * LDK + ks * 32 + lg * 8];
#pragma unroll
            for (int dg = 0; dg < 4; ++dg) {
                bf16x8 vf = *(const bf16x8*)&Vs[(dg * 16 + lq) * LDK + ks * 32 + lg * 8];
                oacc[dg] = __builtin_amdgcn_mfma_f32_16x16x32_bf16(vf, pf, oacc[dg], 0, 0, 0);
            }
        }
    }

    // epilogue: lane holds O^T[d = dg*16 + 4*lg + r][q = lane&15]
    const float inv = 1.f / lrun;
    unsigned short* op = ctx + (size_t)(q0 + lq) * C_ + h * D_;
#pragma unroll
    for (int dg = 0; dg < 4; ++dg) {
        ushort4 o;
        o.x = f2bf(oacc[dg][0] * inv); o.y = f2bf(oacc[dg][1] * inv);
        o.z = f2bf(oacc[dg][2] * inv); o.w = f2bf(oacc[dg][3] * inv);
        *(ushort4*)&op[dg * 16 + lg * 4] = o;
    }
}

// ---------------------------------------------------------------------------
extern "C" void kernel_launch(void* const* d_in, const int* in_sizes, int n_in,
                              void* d_out, int out_size, void* d_ws, size_t ws_size,
                              hipStream_t stream) {
    (void)in_sizes; (void)n_in; (void)out_size; (void)ws_size;
    const float* x  = (const float*)d_in[0];
    const float* Wq = (const float*)d_in[1];
    const float* bq = (const float*)d_in[2];
    const float* Wk = (const float*)d_in[3];
    const float* bk = (const float*)d_in[4];
    const float* Wv = (const float*)d_in[5];
    const float* bv = (const float*)d_in[6];
    const float* Wo = (const float*)d_in[7];
    const float* bo = (const float*)d_in[8];
    float* out = (float*)d_out;

    unsigned short* ws  = (unsigned short*)d_ws;
    unsigned short* xb  = ws;
    unsigned short* Wqb = xb + TC_;
    unsigned short* Wkb = Wqb + CC_;
    unsigned short* Wvb = Wkb + CC_;
    unsigned short* Wob = Wvb + CC_;
    unsigned short* Qb  = Wob + CC_;
    unsigned short* Kb  = Qb + TC_;
    unsigned short* Vtb = Kb + TC_;     // [H][D][T]
    unsigned short* ctxb = Vtb + TC_;

    f2b_kernel<<<2048, 256, 0, stream>>>(x, xb, (int)(TC_ / 4));
    f2b_kernel<<<576, 256, 0, stream>>>(Wq, Wqb, (int)(CC_ / 4));
    f2b_kernel<<<576, 256, 0, stream>>>(Wk, Wkb, (int)(CC_ / 4));
    f2b_kernel<<<576, 256, 0, stream>>>(Wv, Wvb, (int)(CC_ / 4));
    f2b_kernel<<<576, 256, 0, stream>>>(Wo, Wob, (int)(CC_ / 4));

    dim3 gg(T_ / 64, C_ / 64);   // 64 x 12
    // Q pre-scaled by 1/sqrt(D) = 0.125 (exact in bf16)
    gemm16<1><<<gg, 256, 0, stream>>>(xb, Wqb, bq, Qb, T_, C_, C_, 0.125f);
    gemm16<1><<<gg, 256, 0, stream>>>(xb, Wkb, bk, Kb, T_, C_, C_, 1.0f);
    gemm16<2><<<gg, 256, 0, stream>>>(xb, Wvb, bv, Vtb, T_, C_, C_, 1.0f);

    dim3 ga(T_ / 64, H_);        // 64 x 12
    attn16<<<ga, 256, 0, stream>>>(Qb, Kb, Vtb, ctxb);

    gemm16<0><<<gg, 256, 0, stream>>>(ctxb, Wob, bo, out, T_, C_, C_, 1.0f);
}

// Round 3
// 167.236 us; speedup vs baseline: 15.7920x; 1.1261x over previous
//
#include <hip/hip_runtime.h>
#include <math.h>

#define T_ 4096
#define C_ 768
#define H_ 12
#define D_ 64
#define TC_ ((size_t)T_ * C_)
#define CC_ ((size_t)C_ * C_)
#define LDK 72   // attn LDS pad (bf16 elems)

typedef __attribute__((ext_vector_type(8))) __bf16 bf16x8;
typedef __attribute__((ext_vector_type(4))) __bf16 bf16x4;
typedef __attribute__((ext_vector_type(4))) float f32x4;
typedef __attribute__((ext_vector_type(8))) unsigned short u16x8;

static __device__ __forceinline__ float fast_exp2(float x) {
#if __has_builtin(__builtin_amdgcn_exp2f)
    return __builtin_amdgcn_exp2f(x);
#else
    float r;
    asm("v_exp_f32 %0, %1\n\ts_nop 0" : "=v"(r) : "v"(x));
    return r;
#endif
}

// global (16B per lane) -> LDS direct, wave-uniform LDS base
static __device__ __forceinline__ void gload16(const unsigned short* g, unsigned short* l) {
    __builtin_amdgcn_global_load_lds(
        (const __attribute__((address_space(1))) unsigned int*)g,
        (__attribute__((address_space(3))) unsigned int*)l, 16, 0, 0);
}

// ---------------------------------------------------------------------------
// fp32 -> bf16 convert (RNE via hardware cvt), n4 = n/4
// ---------------------------------------------------------------------------
__global__ void f2b_kernel(const float* __restrict__ in,
                           unsigned short* __restrict__ out, int n4) {
    int i = blockIdx.x * blockDim.x + threadIdx.x;
    const int stride = gridDim.x * blockDim.x;
    for (; i < n4; i += stride) {
        float4 v = ((const float4*)in)[i];
        bf16x4 o = { (__bf16)v.x, (__bf16)v.y, (__bf16)v.z, (__bf16)v.w };
        *(bf16x4*)&out[(size_t)i * 4] = o;
    }
}

// ---------------------------------------------------------------------------
// m97-style 128x128 GEMM core: Y = A[M,K] @ W[N,K]^T, BK=64, 4 waves,
// global_load_lds width-16 staging, 16x16x32 bf16 MFMA, acc[4][4] per wave.
// LDS linear [128][64] (layout required by global_load_lds lane order).
// ---------------------------------------------------------------------------
#define BM 128
#define BN 128
#define BKG 64

struct GemmRegs {
    const unsigned short* ag[4];
    const unsigned short* wg[4];
    unsigned short* la[4];
    unsigned short* lw[4];
    int lq, lg, wr, wc;
};

static __device__ __forceinline__ void gemm_setup(
    GemmRegs& R, const unsigned short* A, const unsigned short* W,
    unsigned short* Asm, unsigned short* Bsm, int bm, int bn, int K)
{
    const int tid = threadIdx.x;
    const int wave = tid >> 6, lane = tid & 63;
    R.lq = lane & 15; R.lg = lane >> 4;
    R.wr = wave >> 1; R.wc = wave & 1;
#pragma unroll
    for (int i = 0; i < 4; ++i) {
        const int flat = wave * 256 + i * 64 + lane;   // 0..1023
        const int row = flat >> 3, cb = flat & 7;
        R.ag[i] = A + (size_t)(bm + row) * K + cb * 8;
        R.wg[i] = W + (size_t)(bn + row) * K + cb * 8;
        R.la[i] = Asm + (wave * 4 + i) * 512;
        R.lw[i] = Bsm + (wave * 4 + i) * 512;
    }
}

static __device__ __forceinline__ void gemm_loop(
    GemmRegs& R, unsigned short* Asm, unsigned short* Bsm, int K, f32x4 acc[4][4])
{
    for (int kb = 0; kb < K; kb += BKG) {
        __syncthreads();   // previous tile fully consumed
#pragma unroll
        for (int i = 0; i < 4; ++i) {
            gload16(R.ag[i] + kb, R.la[i]);
            gload16(R.wg[i] + kb, R.lw[i]);
        }
        __syncthreads();   // staged (compiler drains vmcnt at barrier)
        __builtin_amdgcn_s_setprio(1);
#pragma unroll
        for (int ks = 0; ks < 2; ++ks) {
            bf16x8 af[4], wf[4];
#pragma unroll
            for (int m = 0; m < 4; ++m)
                af[m] = *(const bf16x8*)&Asm[(R.wr * 64 + m * 16 + R.lq) * BKG + ks * 32 + R.lg * 8];
#pragma unroll
            for (int n = 0; n < 4; ++n)
                wf[n] = *(const bf16x8*)&Bsm[(R.wc * 64 + n * 16 + R.lq) * BKG + ks * 32 + R.lg * 8];
#pragma unroll
            for (int m = 0; m < 4; ++m)
#pragma unroll
                for (int n = 0; n < 4; ++n)
                    acc[m][n] = __builtin_amdgcn_mfma_f32_16x16x32_bf16(af[m], wf[n], acc[m][n], 0, 0, 0);
        }
        __builtin_amdgcn_s_setprio(0);
    }
}

// Fused QKV projection: blockIdx.z selects {Q (scaled, bf16), K (bf16), V (bf16, head-transposed)}
__global__ __launch_bounds__(256) void qkv128(
    const unsigned short* __restrict__ xb,
    const unsigned short* __restrict__ Wqb, const unsigned short* __restrict__ Wkb,
    const unsigned short* __restrict__ Wvb,
    const float* __restrict__ bq, const float* __restrict__ bk, const float* __restrict__ bv,
    unsigned short* __restrict__ Qb, unsigned short* __restrict__ Kb,
    unsigned short* __restrict__ Vtb)
{
    __shared__ unsigned short Asm[BM * BKG];
    __shared__ unsigned short Bsm[BN * BKG];
    const int z = blockIdx.z;
    const unsigned short* W = (z == 0) ? Wqb : (z == 1) ? Wkb : Wvb;
    const float* bias = (z == 0) ? bq : (z == 1) ? bk : bv;
    const int bm = blockIdx.x * BM, bn = blockIdx.y * BN;

    GemmRegs R;
    gemm_setup(R, xb, W, Asm, Bsm, bm, bn, C_);
    f32x4 acc[4][4] = {};
    gemm_loop(R, Asm, Bsm, C_, acc);

    // 0.125 * log2(e): QK^T scores land in log2 domain
    const float sc = (z == 0) ? 0.18033688011112042f : 1.0f;
#pragma unroll
    for (int mt = 0; mt < 4; ++mt) {
        const int m0 = bm + R.wr * 64 + mt * 16 + R.lg * 4;
#pragma unroll
        for (int nt = 0; nt < 4; ++nt) {
            const int n = bn + R.wc * 64 + nt * 16 + R.lq;
            const float b = bias[n];
            if (z == 2) {
                // Vt[h][d][t] flat = n*T + t : 4 consecutive t -> one 8B store
                bf16x4 o = { (__bf16)(acc[mt][nt][0] + b), (__bf16)(acc[mt][nt][1] + b),
                             (__bf16)(acc[mt][nt][2] + b), (__bf16)(acc[mt][nt][3] + b) };
                *(bf16x4*)&Vtb[(size_t)n * T_ + m0] = o;
            } else {
                unsigned short* Y = (z == 0) ? Qb : Kb;
#pragma unroll
                for (int r = 0; r < 4; ++r)
                    Y[(size_t)(m0 + r) * C_ + n] =
                        __builtin_bit_cast(unsigned short, (__bf16)((acc[mt][nt][r] + b) * sc));
            }
        }
    }
}

// Output projection: fp32 out + bias
__global__ __launch_bounds__(256) void out128(
    const unsigned short* __restrict__ ctxb, const unsigned short* __restrict__ Wob,
    const float* __restrict__ bo, float* __restrict__ out)
{
    __shared__ unsigned short Asm[BM * BKG];
    __shared__ unsigned short Bsm[BN * BKG];
    const int bm = blockIdx.x * BM, bn = blockIdx.y * BN;

    GemmRegs R;
    gemm_setup(R, ctxb, Wob, Asm, Bsm, bm, bn, C_);
    f32x4 acc[4][4] = {};
    gemm_loop(R, Asm, Bsm, C_, acc);

#pragma unroll
    for (int mt = 0; mt < 4; ++mt) {
        const int m0 = bm + R.wr * 64 + mt * 16 + R.lg * 4;
#pragma unroll
        for (int nt = 0; nt < 4; ++nt) {
            const int n = bn + R.wc * 64 + nt * 16 + R.lq;
            const float b = bo[n];
#pragma unroll
            for (int r = 0; r < 4; ++r)
                out[(size_t)(m0 + r) * C_ + n] = acc[mt][nt][r] + b;
        }
    }
}

// ---------------------------------------------------------------------------
// Flash attention, bf16 MFMA, base-2 online softmax with defer-max (T13).
// Block = (64 q-rows, head); 4 waves, wave owns 16 q. Swapped QK^T.
// Q pre-scaled by 0.125*log2(e) in projection -> scores in log2 units.
// 2 barriers/tile (P buffer is per-wave -> no 3rd barrier needed).
// ---------------------------------------------------------------------------
__global__ __launch_bounds__(256) void attn16(
    const unsigned short* __restrict__ Qb, const unsigned short* __restrict__ Kb,
    const unsigned short* __restrict__ Vtb, unsigned short* __restrict__ ctx)
{
    __shared__ unsigned short Ks[64 * LDK];     // [kv][d]
    __shared__ unsigned short Vs[64 * LDK];     // [d][kv]
    __shared__ unsigned short Ps[4][16 * LDK];  // per wave: [q][kv]

    const int tid = threadIdx.x;
    const int wave = tid >> 6, lane = tid & 63;
    const int lq = lane & 15, lg = lane >> 4;
    const int h = blockIdx.y;
    const int q0 = blockIdx.x * 64 + wave * 16;
    const int srow = tid >> 2, sblk = tid & 3;

    const unsigned short* qp = Qb + (size_t)(q0 + lq) * C_ + h * D_ + lg * 8;
    const bf16x8 qf0 = *(const bf16x8*)qp;
    const bf16x8 qf1 = *(const bf16x8*)(qp + 32);

    f32x4 oacc[4] = {};
    float mrun = -3.4e38f, lrun = 0.f;

    const unsigned short* kg = Kb + (size_t)srow * C_ + h * D_ + sblk * 16;
    const unsigned short* vg = Vtb + (size_t)(h * D_ + srow) * T_ + sblk * 16;

    for (int kv0 = 0; kv0 < T_; kv0 += 64) {
        // issue global loads early (overlap prev PV)
        u16x8 k0 = *(const u16x8*)(kg + (size_t)kv0 * C_);
        u16x8 k1 = *(const u16x8*)(kg + (size_t)kv0 * C_ + 8);
        u16x8 v0 = *(const u16x8*)(vg + kv0);
        u16x8 v1 = *(const u16x8*)(vg + kv0 + 8);
        __syncthreads();   // prev tile fully consumed
        *(u16x8*)&Ks[srow * LDK + sblk * 16] = k0;
        *(u16x8*)&Ks[srow * LDK + sblk * 16 + 8] = k1;
        *(u16x8*)&Vs[srow * LDK + sblk * 16] = v0;
        *(u16x8*)&Vs[srow * LDK + sblk * 16 + 8] = v1;
        __syncthreads();   // staged

        // S^T tiles (scores in log2 units)
        f32x4 sacc[4] = {};
        __builtin_amdgcn_s_setprio(1);
#pragma unroll
        for (int t = 0; t < 4; ++t) {
            bf16x8 a0 = *(const bf16x8*)&Ks[(t * 16 + lq) * LDK + lg * 8];
            sacc[t] = __builtin_amdgcn_mfma_f32_16x16x32_bf16(a0, qf0, sacc[t], 0, 0, 0);
            bf16x8 a1 = *(const bf16x8*)&Ks[(t * 16 + lq) * LDK + 32 + lg * 8];
            sacc[t] = __builtin_amdgcn_mfma_f32_16x16x32_bf16(a1, qf1, sacc[t], 0, 0, 0);
        }
        __builtin_amdgcn_s_setprio(0);

        // online softmax, base 2; lane holds s[kv = t*16 + 4*lg + r] of q-row lq
        float s[16];
        float mt = -3.4e38f;
#pragma unroll
        for (int t = 0; t < 4; ++t)
#pragma unroll
            for (int r = 0; r < 4; ++r) {
                const float v = sacc[t][r];
                s[t * 4 + r] = v;
                mt = fmaxf(mt, v);
            }
        mt = fmaxf(mt, __shfl_xor(mt, 16));
        mt = fmaxf(mt, __shfl_xor(mt, 32));
        // defer-max: only rescale when tile max exceeds running max by >8 (p <= 2^8)
        if (__any(mt > mrun + 8.0f)) {
            const float mnew = fmaxf(mrun, mt);
            const float fsc = fast_exp2(mrun - mnew);   // first tile: 0
            lrun *= fsc;
#pragma unroll
            for (int t = 0; t < 4; ++t)
#pragma unroll
                for (int r = 0; r < 4; ++r) oacc[t][r] *= fsc;
            mrun = mnew;
        }
        float psum = 0.f;
#pragma unroll
        for (int i = 0; i < 16; ++i) { s[i] = fast_exp2(s[i] - mrun); psum += s[i]; }
        psum += __shfl_xor(psum, 16);
        psum += __shfl_xor(psum, 32);
        lrun += psum;

        // P (bf16) -> per-wave LDS (no barrier: same-wave producer/consumer)
#pragma unroll
        for (int t = 0; t < 4; ++t) {
            bf16x4 p4 = { (__bf16)s[t * 4 + 0], (__bf16)s[t * 4 + 1],
                          (__bf16)s[t * 4 + 2], (__bf16)s[t * 4 + 3] };
            *(bf16x4*)&Ps[wave][lq * LDK + t * 16 + lg * 4] = p4;
        }

        // O^T += V^T @ P^T
        __builtin_amdgcn_s_setprio(1);
#pragma unroll
        for (int ks = 0; ks < 2; ++ks) {
            bf16x8 pf = *(const bf16x8*)&Ps[wave][lq * LDK + ks * 32 + lg * 8];
#pragma unroll
            for (int dg = 0; dg < 4; ++dg) {
                bf16x8 vf = *(const bf16x8*)&Vs[(dg * 16 + lq) * LDK + ks * 32 + lg * 8];
                oacc[dg] = __builtin_amdgcn_mfma_f32_16x16x32_bf16(vf, pf, oacc[dg], 0, 0, 0);
            }
        }
        __builtin_amdgcn_s_setprio(0);
    }

    const float inv = 1.f / lrun;
    unsigned short* op = ctx + (size_t)(q0 + lq) * C_ + h * D_;
#pragma unroll
    for (int dg = 0; dg < 4; ++dg) {
        bf16x4 o4 = { (__bf16)(oacc[dg][0] * inv), (__bf16)(oacc[dg][1] * inv),
                      (__bf16)(oacc[dg][2] * inv), (__bf16)(oacc[dg][3] * inv) };
        *(bf16x4*)&op[dg * 16 + lg * 4] = o4;
    }
}

// ---------------------------------------------------------------------------
extern "C" void kernel_launch(void* const* d_in, const int* in_sizes, int n_in,
                              void* d_out, int out_size, void* d_ws, size_t ws_size,
                              hipStream_t stream) {
    (void)in_sizes; (void)n_in; (void)out_size; (void)ws_size;
    const float* x  = (const float*)d_in[0];
    const float* Wq = (const float*)d_in[1];
    const float* bq = (const float*)d_in[2];
    const float* Wk = (const float*)d_in[3];
    const float* bk = (const float*)d_in[4];
    const float* Wv = (const float*)d_in[5];
    const float* bv = (const float*)d_in[6];
    const float* Wo = (const float*)d_in[7];
    const float* bo = (const float*)d_in[8];
    float* out = (float*)d_out;

    unsigned short* ws   = (unsigned short*)d_ws;
    unsigned short* xb   = ws;
    unsigned short* Wqb  = xb + TC_;
    unsigned short* Wkb  = Wqb + CC_;
    unsigned short* Wvb  = Wkb + CC_;
    unsigned short* Wob  = Wvb + CC_;
    unsigned short* Qb   = Wob + CC_;
    unsigned short* Kb   = Qb + TC_;
    unsigned short* Vtb  = Kb + TC_;     // [H][D][T]
    unsigned short* ctxb = Vtb + TC_;

    f2b_kernel<<<2048, 256, 0, stream>>>(x, xb, (int)(TC_ / 4));
    f2b_kernel<<<576, 256, 0, stream>>>(Wq, Wqb, (int)(CC_ / 4));
    f2b_kernel<<<576, 256, 0, stream>>>(Wk, Wkb, (int)(CC_ / 4));
    f2b_kernel<<<576, 256, 0, stream>>>(Wv, Wvb, (int)(CC_ / 4));
    f2b_kernel<<<576, 256, 0, stream>>>(Wo, Wob, (int)(CC_ / 4));

    dim3 gq(T_ / BM, C_ / BN, 3);   // 32 x 6 x 3
    qkv128<<<gq, 256, 0, stream>>>(xb, Wqb, Wkb, Wvb, bq, bk, bv, Qb, Kb, Vtb);

    dim3 ga(T_ / 64, H_);           // 64 x 12
    attn16<<<ga, 256, 0, stream>>>(Qb, Kb, Vtb, ctxb);

    dim3 go(T_ / BM, C_ / BN);      // 32 x 6
    out128<<<go, 256, 0, stream>>>(ctxb, Wob, bo, out);
}